// Round 11
// baseline (70.988 us; speedup 1.0000x reference)
//
#include <hip/hip_runtime.h>

#define N   4096
#define ON  4090
#define NN  (N * N)
#define H   14                        // output rows per strip
#define GRIDY ((ON + H - 1) / H)      // 293 row strips
#define NB  (4 * GRIDY)               // 4 x-segments (1024 wide) x 293 = 1172

// Load 10 consecutive floats of input row gy starting at col ox into wr[0..9].
// Linear-index clamps keep the tail loads in-bounds at the image end; clamped
// (or row-crossing) values land only in wr slots consumed by store-guarded
// outputs (valid outputs never need cols > 4095).
__device__ __forceinline__ void load_row(const float* __restrict__ x,
                                         int gy, int ox, float* wr) {
    const int lb = (gy << 12) + ox;
    const int l0 = min(lb,     NN - 4);   // stays 16B-aligned
    const int l1 = min(lb + 4, NN - 4);
    const int l2 = min(lb + 8, NN - 2);   // stays 8B-aligned
    const float4 a = *reinterpret_cast<const float4*>(x + l0);
    const float4 b = *reinterpret_cast<const float4*>(x + l1);
    const float2 c = *reinterpret_cast<const float2*>(x + l2);
    wr[0]=a.x; wr[1]=a.y; wr[2]=a.z; wr[3]=a.w;
    wr[4]=b.x; wr[5]=b.y; wr[6]=b.z; wr[7]=b.w;
    wr[8]=c.x; wr[9]=c.y;
}

// Register sliding-window 7x7 valid conv. No LDS, no barriers.
// Thread: 4-wide x 14-tall strip; 8-slot register row window, prefetch
// distance 1 row. Block: 4 waves x-contiguous -> 4KB contiguous stores/row.
__global__ __launch_bounds__(256, 4)
void conv7x7_stream(const float* __restrict__ x,
                    const float* __restrict__ w,
                    const float* __restrict__ bias,
                    float* __restrict__ out)
{
    // bijective XCD-chunk swizzle (NB = 1172 = 8*146 + 4): XCD k owns a
    // contiguous strip band -> y-halo re-reads hit that XCD's L2.
    const int b   = blockIdx.x;
    const int q   = NB >> 3, rmd = NB & 7;
    const int xcd = b & 7,   ib  = b >> 3;
    const int t   = (xcd < rmd) ? xcd * (q + 1) + ib
                                : rmd * (q + 1) + (xcd - rmd) * q + ib;
    const int sx  = t & 3;            // x-segment (1024 floats)
    const int sy  = t >> 2;           // row strip

    const int tid  = threadIdx.x;
    const int lane = tid & 63;
    const int wv   = tid >> 6;
    const int ox   = (sx << 10) + (wv << 8) + (lane << 2);   // lane col base
    const int y0   = sy * H;

    // weights/bias: uniform -> scalar loads, live in SGPRs
    float ws[49];
    #pragma unroll
    for (int i = 0; i < 49; ++i) ws[i] = w[i];
    const float bv = bias[0];

    float win[8][10];   // all indices compile-time after unroll -> registers

    // preload input rows y0 .. y0+6
    #pragma unroll
    for (int s = 0; s < 7; ++s)
        load_row(x, min(y0 + s, N - 1), ox, win[s]);

    const bool inx = (ox + 4 <= ON);

    #pragma unroll
    for (int r = 0; r < H; ++r) {
        // prefetch input row y0+r+7 into the free slot (used next iter)
        load_row(x, min(y0 + r + 7, N - 1), ox, win[(r + 7) & 7]);

        float acc0 = 0.f, acc1 = 0.f, acc2 = 0.f, acc3 = 0.f;
        #pragma unroll
        for (int ky = 0; ky < 7; ++ky) {
            const float* rw = win[(r + ky) & 7];
            #pragma unroll
            for (int kx = 0; kx < 7; ++kx) {
                const float wk = ws[ky * 7 + kx];
                acc0 = fmaf(rw[kx],     wk, acc0);
                acc1 = fmaf(rw[kx + 1], wk, acc1);
                acc2 = fmaf(rw[kx + 2], wk, acc2);
                acc3 = fmaf(rw[kx + 3], wk, acc3);
            }
        }

        const int oy = y0 + r;
        if (oy < ON) {
            if (inx) {
                float* dst = out + (size_t)oy * ON + ox;      // 8B-aligned
                *reinterpret_cast<float2*>(dst)     = make_float2(acc0 + bv, acc1 + bv);
                *reinterpret_cast<float2*>(dst + 2) = make_float2(acc2 + bv, acc3 + bv);
            } else {
                float* dst = out + (size_t)oy * ON;
                if (ox     < ON) dst[ox]     = acc0 + bv;
                if (ox + 1 < ON) dst[ox + 1] = acc1 + bv;
                if (ox + 2 < ON) dst[ox + 2] = acc2 + bv;
                if (ox + 3 < ON) dst[ox + 3] = acc3 + bv;
            }
        }
    }
}

extern "C" void kernel_launch(void* const* d_in, const int* in_sizes, int n_in,
                              void* d_out, int out_size, void* d_ws, size_t ws_size,
                              hipStream_t stream) {
    const float* x    = (const float*)d_in[0];
    const float* w    = (const float*)d_in[1];
    const float* bias = (const float*)d_in[2];
    float* out        = (float*)d_out;

    conv7x7_stream<<<dim3(NB, 1, 1), dim3(256, 1, 1), 0, stream>>>(x, w, bias, out);
}

// Round 12
// 57.951 us; speedup vs baseline: 1.2250x; 1.2250x over previous
//
#include <hip/hip_runtime.h>

#define N   4096
#define ON  4090
#define BW  128        // block output tile width
#define BH  32         // block output tile height
#define IR  38         // staged input rows (BH + 6)
#define ICC 40         // float4 chunks per staged row (160 cols)
#define NCH (IR * ICC) // 1520 staging chunks
#define LW  168        // LDS row pitch in bf16 units (336 B: 16B-aligned, 20 banks mod 32 -> conflict-free)
#define GXB 32
#define GYB 128
#define NB  (GXB * GYB)   // 4096 blocks (divisible by 8 -> simple XCD chunking)

typedef short  bf16x8 __attribute__((ext_vector_type(8)));
typedef float  f32x4  __attribute__((ext_vector_type(4)));
typedef unsigned short u16;
typedef unsigned short u16x4 __attribute__((ext_vector_type(4)));

__device__ __forceinline__ u16 f2bf(float f) {   // fp32 -> bf16 RNE (inputs finite)
    unsigned u = __builtin_bit_cast(unsigned, f);
    u += 0x7fffu + ((u >> 16) & 1u);
    return (u16)(u >> 16);
}

// 7x7 valid conv as 7 Toeplitz-band MFMAs per 16x16 output tile:
//   D[m][n] = sum_ky A_ky . B_ky,  A_ky[m][k] = xbf[y0+ky+m][x0+k] (K=32),
//   B_ky[k][n] = w[ky][k-n] for 0<=k-n<7 else 0  (constant frags, 28 VGPRs).
// Fragment layouts (gfx950 16x16x32): A: m=lane&15, k=8*(lane>>4)+j;
// B: n=lane&15, k=8*(lane>>4)+j; D: col=lane&15, row=4*(lane>>4)+r (m89-verified).
__global__ __launch_bounds__(256, 5)
void conv7x7_mfma(const float* __restrict__ x,
                  const float* __restrict__ w,
                  const float* __restrict__ bias,
                  float* __restrict__ out)
{
    __shared__ u16   tile[IR * LW];   // 12,768 B bf16 input tile
    __shared__ float wt[7 * 47];      // Toeplitz weight table, wt[ky][15+d]

    const int tid  = threadIdx.x;
    const int lane = tid & 63;
    const int wv   = tid >> 6;

    // XCD-chunked swizzle: XCD k owns contiguous block range -> L2 locality
    const int b  = blockIdx.x;
    const int bs = (b & 7) * (NB / 8) + (b >> 3);
    const int bx = bs & (GXB - 1);
    const int by = bs >> 5;
    const int x0 = bx * BW;
    const int y0 = by * BH;

    // ---- Toeplitz table (single pass, no intra-table race) ----
    for (int idx = tid; idx < 7 * 47; idx += 256) {
        const int ky = idx / 47;
        const int d  = idx - ky * 47 - 15;
        wt[idx] = (d >= 0 && d < 7) ? w[ky * 7 + d] : 0.0f;
    }

    // ---- stage 38 x 160 input cols, fp32 -> bf16 fused ----
    // col chunks fully OOB (>4095, only x0=3968) clamp to 4092: finite junk
    // that meets only zero weights or store-guarded outputs. Rows clamp to 4095.
    #pragma unroll
    for (int i = 0; i < 6; ++i) {
        const int q = tid + (i << 8);
        if (q < NCH) {
            const int row  = q / ICC;
            const int cc   = q - row * ICC;
            const int gy   = min(y0 + row, N - 1);
            const int gcol = min(x0 + (cc << 2), N - 4);
            const float4 v = *reinterpret_cast<const float4*>(
                x + ((size_t)gy << 12) + gcol);
            u16x4 p;
            p.x = f2bf(v.x); p.y = f2bf(v.y); p.z = f2bf(v.z); p.w = f2bf(v.w);
            *reinterpret_cast<u16x4*>(&tile[row * LW + (cc << 2)]) = p;
        }
    }

    const float bv = bias[0];
    __syncthreads();

    // ---- build the 7 Toeplitz B-fragments (once per wave) ----
    const int nn = lane & 15;          // B col / D col / A row
    const int hh = lane >> 4;          // k-group
    bf16x8 bfrag[7];
    #pragma unroll
    for (int ky = 0; ky < 7; ++ky) {
        bf16x8 bb;
        #pragma unroll
        for (int j = 0; j < 8; ++j) {
            const int t = 15 + (hh << 3) + j - nn;    // 0..46
            bb[j] = (short)f2bf(wt[ky * 47 + t]);
        }
        bfrag[ky] = bb;
    }

    // ---- 4 tiles per wave: col-tiles {2wv, 2wv+1} x row-tiles {0,1} ----
    f32x4 acc[2][2] = {{{0.f,0.f,0.f,0.f},{0.f,0.f,0.f,0.f}},
                       {{0.f,0.f,0.f,0.f},{0.f,0.f,0.f,0.f}}};

    #pragma unroll
    for (int ky = 0; ky < 7; ++ky) {
        #pragma unroll
        for (int rt = 0; rt < 2; ++rt) {
            const int arow = (rt << 4) + ky + nn;     // <= 37
            #pragma unroll
            for (int c = 0; c < 2; ++c) {
                const int acol = ((wv * 2 + c) << 4) + (hh << 3);   // <= 136
                const bf16x8 af = *reinterpret_cast<const bf16x8*>(
                    &tile[arow * LW + acol]);         // 16B-aligned ds_read_b128
                acc[rt][c] = __builtin_amdgcn_mfma_f32_16x16x32_bf16(
                    af, bfrag[ky], acc[rt][c], 0, 0, 0);
            }
        }
    }

    // ---- store (+bias), non-temporal; guards only on edge blocks ----
    const bool interior = (x0 + BW <= ON) && (y0 + BH <= ON);
    #pragma unroll
    for (int rt = 0; rt < 2; ++rt) {
        #pragma unroll
        for (int c = 0; c < 2; ++c) {
            const int oxx = x0 + ((wv * 2 + c) << 4) + nn;
            const int oyb = y0 + (rt << 4) + (hh << 2);
            #pragma unroll
            for (int r = 0; r < 4; ++r) {
                const int oy = oyb + r;
                if (interior || (oy < ON && oxx < ON))
                    __builtin_nontemporal_store(acc[rt][c][r] + bv,
                                                out + (size_t)oy * ON + oxx);
            }
        }
    }
}

extern "C" void kernel_launch(void* const* d_in, const int* in_sizes, int n_in,
                              void* d_out, int out_size, void* d_ws, size_t ws_size,
                              hipStream_t stream) {
    const float* x    = (const float*)d_in[0];
    const float* w    = (const float*)d_in[1];
    const float* bias = (const float*)d_in[2];
    float* out        = (float*)d_out;

    conv7x7_mfma<<<dim3(NB, 1, 1), dim3(256, 1, 1), 0, stream>>>(x, w, bias, out);
}

// Round 13
// 42.457 us; speedup vs baseline: 1.6720x; 1.3649x over previous
//
#include <hip/hip_runtime.h>

#define N   4096
#define ON  4090
#define BW  128        // block output tile width
#define BH  32         // block output tile height
#define IR  38         // staged input rows (BH + 6)
#define ICC 40         // float4 chunks per staged row (160 cols)
#define NCH (IR * ICC) // 1520 staging chunks
#define LW  168        // bf16 LDS row pitch (336 B, 16B-aligned)
#define EP  36         // epilogue LDS pitch in floats (144 B, 16B-aligned)
#define GXB 32
#define GYB 128
#define NB  (GXB * GYB)   // 4096 blocks (divisible by 8)

typedef short  bf16x8 __attribute__((ext_vector_type(8)));
typedef float  f32x4  __attribute__((ext_vector_type(4)));
typedef unsigned short u16;
typedef unsigned short u16x4 __attribute__((ext_vector_type(4)));

__device__ __forceinline__ u16 f2bf(float f) {   // fp32 -> bf16 RNE (finite)
    unsigned u = __builtin_bit_cast(unsigned, f);
    u += 0x7fffu + ((u >> 16) & 1u);
    return (u16)(u >> 16);
}

// 7x7 valid conv = 7 Toeplitz-band MFMAs (16x16x32 bf16) per 16x16 out tile.
// Epilogue: acc -> wave-private LDS slice -> row-contiguous float2 stores
// (allocating, so L2 merges partial 64B lines across x-neighbor blocks).
__global__ __launch_bounds__(256, 8)
void conv7x7_mfma(const float* __restrict__ x,
                  const float* __restrict__ w,
                  const float* __restrict__ bias,
                  float* __restrict__ out)
{
    __shared__ float smem[4 * 32 * EP];   // 18,432 B: input tile / epilogue union
    __shared__ float wt[7 * 47];          // Toeplitz weight table wt[ky][15+d]
    u16* tile = reinterpret_cast<u16*>(smem);

    const int tid  = threadIdx.x;
    const int lane = tid & 63;
    const int wv   = tid >> 6;

    // XCD-chunked swizzle: XCD k owns a contiguous block range -> L2 locality
    const int b  = blockIdx.x;
    const int bs = (b & 7) * (NB / 8) + (b >> 3);
    const int bx = bs & (GXB - 1);
    const int by = bs >> 5;
    const int x0 = bx * BW;
    const int y0 = by * BH;

    // ---- Toeplitz table ----
    for (int idx = tid; idx < 7 * 47; idx += 256) {
        const int ky = idx / 47;
        const int d  = idx - ky * 47 - 15;
        wt[idx] = (d >= 0 && d < 7) ? w[ky * 7 + d] : 0.0f;
    }

    // ---- stage 38 x 160 input cols, fp32 -> bf16 fused ----
    #pragma unroll
    for (int i = 0; i < 6; ++i) {
        const int q = tid + (i << 8);
        if (q < NCH) {
            const int row  = q / ICC;
            const int cc   = q - row * ICC;
            const int gy   = min(y0 + row, N - 1);
            const int gcol = min(x0 + (cc << 2), N - 4);
            const float4 v = *reinterpret_cast<const float4*>(
                x + ((size_t)gy << 12) + gcol);
            u16x4 p;
            p.x = f2bf(v.x); p.y = f2bf(v.y); p.z = f2bf(v.z); p.w = f2bf(v.w);
            *reinterpret_cast<u16x4*>(&tile[row * LW + (cc << 2)]) = p;
        }
    }

    const float bv = bias[0];
    __syncthreads();

    // ---- build 7 Toeplitz B-fragments ----
    const int nn = lane & 15;          // B col / A row / D col
    const int hh = lane >> 4;          // k-group / D row-group
    bf16x8 bfrag[7];
    #pragma unroll
    for (int ky = 0; ky < 7; ++ky) {
        bf16x8 bb;
        #pragma unroll
        for (int j = 0; j < 8; ++j) {
            const int t = 15 + (hh << 3) + j - nn;    // 0..46
            bb[j] = (short)f2bf(wt[ky * 47 + t]);
        }
        bfrag[ky] = bb;
    }

    // ---- MFMA: 4 tiles/wave (2 col-tiles x 2 row-tiles) ----
    f32x4 acc[2][2] = {{{0.f,0.f,0.f,0.f},{0.f,0.f,0.f,0.f}},
                       {{0.f,0.f,0.f,0.f},{0.f,0.f,0.f,0.f}}};

    #pragma unroll
    for (int ky = 0; ky < 7; ++ky) {
        #pragma unroll
        for (int rt = 0; rt < 2; ++rt) {
            const int arow = (rt << 4) + ky + nn;     // <= 37
            #pragma unroll
            for (int c = 0; c < 2; ++c) {
                const int acol = ((wv * 2 + c) << 4) + (hh << 3);   // <= 136
                const bf16x8 af = *reinterpret_cast<const bf16x8*>(
                    &tile[arow * LW + acol]);         // 16B-aligned b128
                acc[rt][c] = __builtin_amdgcn_mfma_f32_16x16x32_bf16(
                    af, bfrag[ky], acc[rt][c], 0, 0, 0);
            }
        }
    }

    __syncthreads();   // all tile reads done; reuse smem for epilogue

    // ---- epilogue: acc -> wave-private LDS slice (32 x EP) ----
    float* lbuf = smem + wv * (32 * EP);
    #pragma unroll
    for (int rt = 0; rt < 2; ++rt)
        #pragma unroll
        for (int c = 0; c < 2; ++c)
            #pragma unroll
            for (int r = 0; r < 4; ++r)
                lbuf[((rt << 4) + (hh << 2) + r) * EP + (c << 4) + nn] =
                    acc[rt][c][r];

    // wave-private slice: in-wave RAW, lgkmcnt ordering suffices (no barrier)
    const int row = lane >> 1;            // 0..31
    const int ch  = (lane & 1) << 4;      // 0 / 16
    const float* lp = lbuf + row * EP + ch;
    const int oy  = y0 + row;
    const int oxb = x0 + (wv << 5) + ch;

    f32x4 v0 = *reinterpret_cast<const f32x4*>(lp);
    f32x4 v1 = *reinterpret_cast<const f32x4*>(lp + 4);
    f32x4 v2 = *reinterpret_cast<const f32x4*>(lp + 8);
    f32x4 v3 = *reinterpret_cast<const f32x4*>(lp + 12);

    if (oy < ON) {
        float* dst = out + (size_t)oy * ON + oxb;
        if (oxb + 16 <= ON) {            // 8B-aligned float2 stores (merge in L2)
            *reinterpret_cast<float2*>(dst)      = make_float2(v0[0]+bv, v0[1]+bv);
            *reinterpret_cast<float2*>(dst + 2)  = make_float2(v0[2]+bv, v0[3]+bv);
            *reinterpret_cast<float2*>(dst + 4)  = make_float2(v1[0]+bv, v1[1]+bv);
            *reinterpret_cast<float2*>(dst + 6)  = make_float2(v1[2]+bv, v1[3]+bv);
            *reinterpret_cast<float2*>(dst + 8)  = make_float2(v2[0]+bv, v2[1]+bv);
            *reinterpret_cast<float2*>(dst + 10) = make_float2(v2[2]+bv, v2[3]+bv);
            *reinterpret_cast<float2*>(dst + 12) = make_float2(v3[0]+bv, v3[1]+bv);
            *reinterpret_cast<float2*>(dst + 14) = make_float2(v3[2]+bv, v3[3]+bv);
        } else {
            const float vv[16] = {v0[0],v0[1],v0[2],v0[3], v1[0],v1[1],v1[2],v1[3],
                                  v2[0],v2[1],v2[2],v2[3], v3[0],v3[1],v3[2],v3[3]};
            #pragma unroll
            for (int j = 0; j < 16; ++j)
                if (oxb + j < ON) dst[j] = vv[j] + bv;
        }
    }
}

extern "C" void kernel_launch(void* const* d_in, const int* in_sizes, int n_in,
                              void* d_out, int out_size, void* d_ws, size_t ws_size,
                              hipStream_t stream) {
    const float* x    = (const float*)d_in[0];
    const float* w    = (const float*)d_in[1];
    const float* bias = (const float*)d_in[2];
    float* out        = (float*)d_out;

    conv7x7_mfma<<<dim3(NB, 1, 1), dim3(256, 1, 1), 0, stream>>>(x, w, bias, out);
}